// Round 2
// baseline (582.636 us; speedup 1.0000x reference)
//
#include <hip/hip_runtime.h>

// SparseNodeLinear: out[b,f,n] = sum_k (mask[n,k] ? 0 : x[b,k,n]) * w[n,k,f] + bias[f,n]
// x: [B, K, N] f32, w: [N, K, F] f32, bias: [F, N] f32, em: [N, K] int32 (bool), out: [B, F, N] f32
// B=8, N=2048, K=2049, F=32.
//
// One block (256 thr) per node n: streams the 256 KB weight slab from HBM exactly
// once (reused in-cache across all 8 batch entries). Memory-bound: ~690 MB total.

constexpr int N_ = 2048;
constexpr int K_ = 2049;
constexpr int F_ = 32;
constexpr int B_ = 8;

__global__ __launch_bounds__(256, 8) void snl_kernel(
    const float* __restrict__ x,
    const float* __restrict__ w,
    const float* __restrict__ bias,
    const int* __restrict__ em,
    float* __restrict__ out)
{
    const int n    = blockIdx.x;
    const int t    = threadIdx.x;
    const int wave = t >> 6;   // 0..3 : k-phase (k = k0 + wave)
    const int lane = t & 63;
    const int b    = lane >> 3; // 0..7
    const int fg   = lane & 7;  // f base = fg*4

    const float* wn  = w  + (size_t)n * K_ * F_;
    const int*   emn = em + (size_t)n * K_;
    const float* xb  = x  + (size_t)b * K_ * N_ + n;  // x[b,k,n] = xb[k*N_]

    float4 acc = make_float4(0.f, 0.f, 0.f, 0.f);

    // main loop: k in [0, 2048), 4 k's per pass (one per wave)
    #pragma unroll 8
    for (int k0 = 0; k0 < 2048; k0 += 4) {
        const int k = k0 + wave;
        const float xraw = xb[(size_t)k * N_];
        const float xv   = (emn[k] != 0) ? 0.0f : xraw;
        const float4 w4  = *reinterpret_cast<const float4*>(wn + (size_t)k * F_ + fg * 4);
        acc.x = fmaf(xv, w4.x, acc.x);
        acc.y = fmaf(xv, w4.y, acc.y);
        acc.z = fmaf(xv, w4.z, acc.z);
        acc.w = fmaf(xv, w4.w, acc.w);
    }
    // tail: k = 2048 handled by wave 0
    if (wave == 0) {
        const int k = 2048;
        const float xraw = xb[(size_t)k * N_];
        const float xv   = (emn[k] != 0) ? 0.0f : xraw;
        const float4 w4  = *reinterpret_cast<const float4*>(wn + (size_t)k * F_ + fg * 4);
        acc.x = fmaf(xv, w4.x, acc.x);
        acc.y = fmaf(xv, w4.y, acc.y);
        acc.z = fmaf(xv, w4.z, acc.z);
        acc.w = fmaf(xv, w4.w, acc.w);
    }

    // cross-wave reduction (4 partial k-phases per output)
    __shared__ float red[4][64][4];
    red[wave][lane][0] = acc.x;
    red[wave][lane][1] = acc.y;
    red[wave][lane][2] = acc.z;
    red[wave][lane][3] = acc.w;
    __syncthreads();

    if (wave == 0) {
        #pragma unroll
        for (int j = 0; j < 4; ++j) {
            const float s = red[0][lane][j] + red[1][lane][j]
                          + red[2][lane][j] + red[3][lane][j];
            const int f = fg * 4 + j;
            out[(size_t)b * F_ * N_ + (size_t)f * N_ + n] = s + bias[f * N_ + n];
        }
    }
}

extern "C" void kernel_launch(void* const* d_in, const int* in_sizes, int n_in,
                              void* d_out, int out_size, void* d_ws, size_t ws_size,
                              hipStream_t stream) {
    const float* x    = (const float*)d_in[0];
    const float* w    = (const float*)d_in[1];
    const float* bias = (const float*)d_in[2];
    const int*   em   = (const int*)d_in[3];
    float*       out  = (float*)d_out;

    snl_kernel<<<dim3(N_), dim3(256), 0, stream>>>(x, w, bias, em, out);
}

// Round 3
// 27.546 us; speedup vs baseline: 21.1514x; 21.1514x over previous
//
#include <hip/hip_runtime.h>

// SparseNodeLinear, sparsity-aware:
//   out[b,f,n] = sum_{k: em[n,k]==0} x[b,k,n] * w[n,k,f] + bias[f,n]
// x: [B,K,N] f32, w: [N,K,F] f32, bias: [F,N] f32, em: [N,K] int32, out: [B,F,N] f32
// B=8, N=2048, K=2049, F=32.  em is ~98.4% nonzero (masked) => ~34 active k per n.
//
// One block per node n. Scan em in tiles of TK=256 k's (active list per tile is
// bounded by TK by construction -> no overflow possible), gather active x into
// LDS, stream only the ~34 active 128-B weight rows. Traffic ~100 MB vs 796 MB
// dense.

constexpr int N_ = 2048;
constexpr int K_ = 2049;
constexpr int F_ = 32;
constexpr int B_ = 8;
constexpr int TK = 256;   // k scan tile (== blockDim)

__global__ __launch_bounds__(256, 8) void snl_sparse_kernel(
    const float* __restrict__ x,
    const float* __restrict__ w,
    const float* __restrict__ bias,
    const int*   __restrict__ em,
    float* __restrict__ out)
{
    const int n = blockIdx.x;
    const int t = threadIdx.x;

    __shared__ int   s_idx[TK];          // active k list for current tile
    __shared__ float s_x[TK][B_];        // gathered x[b, k_j, n]
    __shared__ float s_red[8][B_][F_];   // per-kphase partials
    __shared__ int   s_wtot[4];          // per-wave active counts (scan)

    const int kphase = t >> 5;   // 0..7 : which j residues this thread sums
    const int f      = t & 31;   // 0..31
    const int lane   = t & 63;
    const int wid    = t >> 6;   // wave 0..3

    float acc[B_];
    #pragma unroll
    for (int b = 0; b < B_; ++b) acc[b] = 0.f;

    const int*   emn = em + (size_t)n * K_;
    const float* wn  = w  + (size_t)n * K_ * F_;

    // prefetch first em tile
    int emv = (t < K_) ? emn[t] : 1;

    for (int k0 = 0; k0 < K_; k0 += TK) {
        const int k      = k0 + t;
        const bool active = (k < K_) && (emv == 0);

        // prefetch next em tile early (hides under this tile's phases)
        const int knext = k + TK;
        int emv_next = (knext < K_) ? emn[knext] : 1;

        // --- deterministic ballot-prefix scan -> ordered active list ---
        const unsigned long long bal = __ballot(active);
        const int woff = __popcll(bal & ((1ull << lane) - 1ull));
        if (lane == 0) s_wtot[wid] = __popcll(bal);
        __syncthreads();
        int wbase = 0;
        #pragma unroll
        for (int i = 0; i < 4; ++i) wbase += (i < wid) ? s_wtot[i] : 0;
        const int ct = s_wtot[0] + s_wtot[1] + s_wtot[2] + s_wtot[3];
        if (active) s_idx[wbase + woff] = k;
        __syncthreads();

        // --- gather x[b, k_j, n] into LDS ---
        for (int jj = t; jj < ct * B_; jj += 256) {
            const int j  = jj >> 3;
            const int b  = jj & 7;
            const int kj = s_idx[j];
            s_x[j][b] = x[((size_t)b * K_ + kj) * N_ + n];
        }
        __syncthreads();

        // --- compute: thread (kphase, f) handles j = kphase, kphase+8, ... ---
        for (int j = kphase; j < ct; j += 8) {
            const int kj   = s_idx[j];
            const float wv = wn[(size_t)kj * F_ + f];          // coalesced 128B/row
            const float4 x0 = *reinterpret_cast<const float4*>(&s_x[j][0]);
            const float4 x1 = *reinterpret_cast<const float4*>(&s_x[j][4]);
            acc[0] = fmaf(x0.x, wv, acc[0]);
            acc[1] = fmaf(x0.y, wv, acc[1]);
            acc[2] = fmaf(x0.z, wv, acc[2]);
            acc[3] = fmaf(x0.w, wv, acc[3]);
            acc[4] = fmaf(x1.x, wv, acc[4]);
            acc[5] = fmaf(x1.y, wv, acc[5]);
            acc[6] = fmaf(x1.z, wv, acc[6]);
            acc[7] = fmaf(x1.w, wv, acc[7]);
        }
        __syncthreads();   // s_idx/s_x reused next tile

        emv = emv_next;
    }

    // --- cross-kphase reduction ---
    #pragma unroll
    for (int b = 0; b < B_; ++b) s_red[kphase][b][f] = acc[b];
    __syncthreads();

    {
        const int b  = t >> 5;
        const int ff = t & 31;
        float s = 0.f;
        #pragma unroll
        for (int p = 0; p < 8; ++p) s += s_red[p][b][ff];
        out[((size_t)b * F_ + ff) * N_ + n] = s + bias[(size_t)ff * N_ + n];
    }
}

extern "C" void kernel_launch(void* const* d_in, const int* in_sizes, int n_in,
                              void* d_out, int out_size, void* d_ws, size_t ws_size,
                              hipStream_t stream) {
    const float* x    = (const float*)d_in[0];
    const float* w    = (const float*)d_in[1];
    const float* bias = (const float*)d_in[2];
    const int*   em   = (const int*)d_in[3];
    float*       out  = (float*)d_out;

    snl_sparse_kernel<<<dim3(N_), dim3(256), 0, stream>>>(x, w, bias, em, out);
}